// Round 2
// baseline (659.674 us; speedup 1.0000x reference)
//
#include <hip/hip_runtime.h>

// Problem constants (from reference; all fp32 I/O)
#define NVIEW 5
#define BATCH 2
#define NB    128000          // NBINS = 80*80*20
#define CI    3
#define CF    32
#define NCH   35              // CI + CF
#define HID   256
#define KP    80              // padded input dim (3 + 35 + 35 = 73 -> 80)
#define IMG_HW 262144         // 512*512
#define FT_HW  16384          // 128*128

// ---------------------------------------------------------------------------
// Kernel 1: transpose feats2d [V][B][32][128][128] -> channels-last
// [V][B][128][128][32] so each bilinear corner is 128B contiguous (2 lines).
// 8 lanes per pixel, each lane handles 4 channels -> one float4 store,
// perfectly coalesced; reads are coalesced within each channel plane.
// ---------------------------------------------------------------------------
__global__ __launch_bounds__(256) void feats_transpose(
    const float* __restrict__ f, float4* __restrict__ ft)
{
    int gid = blockIdx.x * 256 + threadIdx.x;   // 1,310,720 threads
    int pix = gid >> 3;                         // [0, 163840): vb*16384 + (y*128+x)
    int q   = gid & 7;                          // channel-quad (4 ch each)
    int vb  = pix >> 14;
    int rem = pix & 16383;
    const float* src = f + (vb * CF + q * 4) * FT_HW + rem;
    float4 v;
    v.x = src[0 * FT_HW];
    v.y = src[1 * FT_HW];
    v.z = src[2 * FT_HW];
    v.w = src[3 * FT_HW];
    ft[gid] = v;   // [pix][q] -> channels-last
}

// ---------------------------------------------------------------------------
// Kernel 2: fused gather (bilinear, 5 views) -> mean / exp(-var) -> MLP
// One thread per (batch, point). W1 staged in LDS fp32 in two 128-col halves
// (40KB); all LDS reads are wave-uniform broadcasts (no bank conflicts).
// ---------------------------------------------------------------------------
__global__ __launch_bounds__(256) void fused_gather_mlp(
    const float* __restrict__ imgs,    // [V][B][3][512][512]
    const float* __restrict__ featsT,  // [V][B][128][128][32]
    const float* __restrict__ grid,    // [V][NB][2]
    const float* __restrict__ points,  // [NB][3]
    const float* __restrict__ W1,      // [73][256]
    const float* __restrict__ b1,      // [256]
    const float* __restrict__ W2,      // [256]
    const float* __restrict__ b2,      // [1]
    float*       __restrict__ out)     // [B*NB]
{
    __shared__ float W1s[KP * 128];   // 40KB: one half (128 hidden units)
    __shared__ float b1s[HID];
    __shared__ float W2s[HID];

    const int tid = threadIdx.x;
    const int idx = blockIdx.x * 256 + tid;     // [0, 256000)
    const int b   = (idx >= NB) ? 1 : 0;
    const int n   = idx - b * NB;

    // stage biases / W2 (blockDim == HID == 256)
    b1s[tid] = b1[tid];
    W2s[tid] = W2[tid];

    float inp[KP];
    #pragma unroll
    for (int i = 0; i < KP; i++) inp[i] = 0.f;
    inp[0] = points[n * 3 + 0];
    inp[1] = points[n * 3 + 1];
    inp[2] = points[n * 3 + 2];
    // inp[3+c] accumulates sum_v, inp[38+c] accumulates sum_v^2

    #pragma unroll
    for (int v = 0; v < NVIEW; v++) {
        const float2 g = ((const float2*)grid)[v * NB + n];
        float gx = g.x;
        float gy = g.y;

        float val[NCH];
        #pragma unroll
        for (int c = 0; c < NCH; c++) val[c] = 0.f;

        // ---- image sample: 512x512, 3 channels, native [C][H][W] ----
        {
            float ix = (gx + 1.f) * 0.5f * 511.f;
            float iy = (gy + 1.f) * 0.5f * 511.f;
            float x0f = floorf(ix), y0f = floorf(iy);
            float x1f = x0f + 1.f, y1f = y0f + 1.f;
            float wx1 = ix - x0f, wx0 = 1.f - wx1;
            float wy1 = iy - y0f, wy0 = 1.f - wy1;
            const float* base = imgs + (size_t)(v * BATCH + b) * (CI * IMG_HW);
            #pragma unroll
            for (int k = 0; k < 4; k++) {
                float xf = (k & 1) ? x1f : x0f;
                float yf = (k >> 1) ? y1f : y0f;
                float w  = ((k & 1) ? wx1 : wx0) * ((k >> 1) ? wy1 : wy0);
                float vd = (xf >= 0.f && xf <= 511.f && yf >= 0.f && yf <= 511.f) ? 1.f : 0.f;
                w *= vd;
                int xi = (int)fminf(fmaxf(xf, 0.f), 511.f);
                int yi = (int)fminf(fmaxf(yf, 0.f), 511.f);
                int off = yi * 512 + xi;
                val[0] += w * base[off];
                val[1] += w * base[off + IMG_HW];
                val[2] += w * base[off + 2 * IMG_HW];
            }
        }

        // ---- feature sample: 128x128, 32 channels, channels-last ----
        {
            float ix = (gx + 1.f) * 0.5f * 127.f;
            float iy = (gy + 1.f) * 0.5f * 127.f;
            float x0f = floorf(ix), y0f = floorf(iy);
            float x1f = x0f + 1.f, y1f = y0f + 1.f;
            float wx1 = ix - x0f, wx0 = 1.f - wx1;
            float wy1 = iy - y0f, wy0 = 1.f - wy1;
            const float* fb = featsT + (size_t)(v * BATCH + b) * (FT_HW * CF);
            #pragma unroll
            for (int k = 0; k < 4; k++) {
                float xf = (k & 1) ? x1f : x0f;
                float yf = (k >> 1) ? y1f : y0f;
                float w  = ((k & 1) ? wx1 : wx0) * ((k >> 1) ? wy1 : wy0);
                float vd = (xf >= 0.f && xf <= 127.f && yf >= 0.f && yf <= 127.f) ? 1.f : 0.f;
                w *= vd;
                int xi = (int)fminf(fmaxf(xf, 0.f), 127.f);
                int yi = (int)fminf(fmaxf(yf, 0.f), 127.f);
                const float4* p = (const float4*)(fb + (size_t)(yi * 128 + xi) * CF);
                #pragma unroll
                for (int q = 0; q < 8; q++) {
                    float4 f4 = p[q];
                    val[3 + q * 4 + 0] += w * f4.x;
                    val[3 + q * 4 + 1] += w * f4.y;
                    val[3 + q * 4 + 2] += w * f4.z;
                    val[3 + q * 4 + 3] += w * f4.w;
                }
            }
        }

        #pragma unroll
        for (int c = 0; c < NCH; c++) {
            inp[3 + c]  += val[c];
            inp[38 + c] += val[c] * val[c];
        }
    }

    // mean / exp(-var)
    #pragma unroll
    for (int c = 0; c < NCH; c++) {
        float m = inp[3 + c] * 0.2f;
        float q = inp[38 + c] * 0.2f - m * m;
        inp[3 + c]  = m;
        inp[38 + c] = expf(-q);
    }
    // inp[73..79] stay 0 (W1 rows >= 73 staged as 0 too)

    // ---- MLP: 80 x 256 layer1 (two 128-col halves via LDS), fused layer2 ----
    float dot = 0.f;
    for (int h = 0; h < 2; h++) {
        __syncthreads();   // protect previous half's W1s before restaging
        for (int e = tid; e < KP * 128; e += 256) {
            int i  = e >> 7;
            int jp = e & 127;
            W1s[e] = (i < 73) ? W1[i * 256 + h * 128 + jp] : 0.f;
        }
        __syncthreads();
        for (int jc = 0; jc < 32; jc++) {
            int j = h * 128 + jc * 4;
            float4 acc = *(const float4*)&b1s[j];
            #pragma unroll
            for (int i = 0; i < KP; i++) {
                float4 w4 = *(const float4*)&W1s[i * 128 + jc * 4];
                acc.x += inp[i] * w4.x;
                acc.y += inp[i] * w4.y;
                acc.z += inp[i] * w4.z;
                acc.w += inp[i] * w4.w;
            }
            acc.x = fmaxf(acc.x, 0.f);
            acc.y = fmaxf(acc.y, 0.f);
            acc.z = fmaxf(acc.z, 0.f);
            acc.w = fmaxf(acc.w, 0.f);
            dot += acc.x * W2s[j] + acc.y * W2s[j + 1]
                 + acc.z * W2s[j + 2] + acc.w * W2s[j + 3];
        }
    }

    float x  = dot + b2[0];
    float sp = fmaxf(x, 0.f) + log1pf(expf(-fabsf(x)));   // stable softplus
    float alpha = -expm1f(-sp);                            // 1 - exp(-sp)
    out[idx] = alpha;
}

extern "C" void kernel_launch(void* const* d_in, const int* in_sizes, int n_in,
                              void* d_out, int out_size, void* d_ws, size_t ws_size,
                              hipStream_t stream) {
    const float* imgs   = (const float*)d_in[0];
    const float* feats  = (const float*)d_in[1];
    const float* grid   = (const float*)d_in[2];
    const float* points = (const float*)d_in[3];
    const float* W1     = (const float*)d_in[4];
    const float* b1     = (const float*)d_in[5];
    const float* W2     = (const float*)d_in[6];
    const float* b2     = (const float*)d_in[7];
    float* out = (float*)d_out;

    float* featsT = (float*)d_ws;   // 41.9 MB channels-last copy

    feats_transpose<<<dim3(5120), dim3(256), 0, stream>>>(feats, (float4*)d_ws);
    fused_gather_mlp<<<dim3(1000), dim3(256), 0, stream>>>(
        imgs, featsT, grid, points, W1, b1, W2, b2, out);
}

// Round 3
// 428.348 us; speedup vs baseline: 1.5400x; 1.5400x over previous
//
#include <hip/hip_runtime.h>

// Problem constants (from reference; all fp32 I/O)
#define NVIEW 5
#define BATCH 2
#define NB    128000          // NBINS = 80*80*20
#define CI    3
#define CF    32
#define NCH   35              // CI + CF
#define HID   256
#define KA    96              // padded K for the MLP GEMM (73 -> 96 = 3*32)
#define IMG_HW 262144         // 512*512
#define FT_HW  16384          // 128*128

typedef __attribute__((ext_vector_type(8))) short short8;   // 8 bf16 (4 VGPRs)
typedef __attribute__((ext_vector_type(4))) float f32x4;    // MFMA accumulator

__device__ __forceinline__ unsigned short f2bf(float f) {
    unsigned int u = __float_as_uint(f);
    unsigned int r = (u + 0x7fffu + ((u >> 16) & 1u)) >> 16;   // RTNE
    return (unsigned short)r;
}

// ---------------------------------------------------------------------------
// Kernel 1: transpose feats2d [V][B][32][128][128] -> channels-last
// [V][B][128][128][32]. LDS tile so BOTH global read and write are coalesced.
// Block: 64 pixels x 32 channels.
// ---------------------------------------------------------------------------
__global__ __launch_bounds__(256) void feats_transpose(
    const float* __restrict__ f, float4* __restrict__ ft)
{
    __shared__ float tile[32][65];   // pad 65: store-phase reads ~2-way (free)

    const int t = threadIdx.x;
    const int pixbase = blockIdx.x * 64;          // 163840 pix total, 2560 blocks
    const int vb  = pixbase >> 14;
    const int rem = pixbase & 16383;

    // read: wave reads 64 consecutive pixels of one channel plane (coalesced)
    {
        const int p  = t & 63;
        const int cg = t >> 6;                    // 0..3
        #pragma unroll
        for (int it = 0; it < 8; it++) {
            int ch = it * 4 + cg;
            tile[ch][p] = f[(size_t)(vb * CF + ch) * FT_HW + rem + p];
        }
    }
    __syncthreads();
    // write: consecutive threads -> consecutive float4s (coalesced)
    {
        const int q = t & 7;                      // channel-quad
        #pragma unroll
        for (int it = 0; it < 2; it++) {
            int p = it * 32 + (t >> 3);
            float4 v;
            v.x = tile[q * 4 + 0][p];
            v.y = tile[q * 4 + 1][p];
            v.z = tile[q * 4 + 2][p];
            v.w = tile[q * 4 + 3][p];
            ft[(size_t)(pixbase + p) * 8 + q] = v;
        }
    }
}

// ---------------------------------------------------------------------------
// Kernel 2: gather (bilinear, 5 views) -> mean / exp(-var) -> bf16 feature
// rows [B*NB][96] into workspace. One thread per (batch, point). No LDS.
// ---------------------------------------------------------------------------
__global__ __launch_bounds__(256) void gather_features(
    const float* __restrict__ imgs,    // [V][B][3][512][512]
    const float* __restrict__ featsT,  // [V][B][128][128][32]
    const float* __restrict__ grid,    // [V][NB][2]
    const float* __restrict__ points,  // [NB][3]
    unsigned short* __restrict__ A)    // [B*NB][96] bf16
{
    const int idx = blockIdx.x * 256 + threadIdx.x;   // [0, 256000)
    const int b   = (idx >= NB) ? 1 : 0;
    const int n   = idx - b * NB;

    float inp[KA];
    #pragma unroll
    for (int i = 0; i < KA; i++) inp[i] = 0.f;
    inp[0] = points[n * 3 + 0];
    inp[1] = points[n * 3 + 1];
    inp[2] = points[n * 3 + 2];
    // inp[3+c] accumulates sum_v, inp[38+c] accumulates sum_v^2

    #pragma unroll
    for (int v = 0; v < NVIEW; v++) {
        const float2 g = ((const float2*)grid)[v * NB + n];
        float gx = g.x;
        float gy = g.y;

        float val[NCH];
        #pragma unroll
        for (int c = 0; c < NCH; c++) val[c] = 0.f;

        // ---- image sample: 512x512, 3 channels, native [C][H][W] ----
        {
            float ix = (gx + 1.f) * 0.5f * 511.f;
            float iy = (gy + 1.f) * 0.5f * 511.f;
            float x0f = floorf(ix), y0f = floorf(iy);
            float x1f = x0f + 1.f, y1f = y0f + 1.f;
            float wx1 = ix - x0f, wx0 = 1.f - wx1;
            float wy1 = iy - y0f, wy0 = 1.f - wy1;
            const float* base = imgs + (size_t)(v * BATCH + b) * (CI * IMG_HW);
            #pragma unroll
            for (int k = 0; k < 4; k++) {
                float xf = (k & 1) ? x1f : x0f;
                float yf = (k >> 1) ? y1f : y0f;
                float w  = ((k & 1) ? wx1 : wx0) * ((k >> 1) ? wy1 : wy0);
                float vd = (xf >= 0.f && xf <= 511.f && yf >= 0.f && yf <= 511.f) ? 1.f : 0.f;
                w *= vd;
                int xi = (int)fminf(fmaxf(xf, 0.f), 511.f);
                int yi = (int)fminf(fmaxf(yf, 0.f), 511.f);
                int off = yi * 512 + xi;
                val[0] += w * base[off];
                val[1] += w * base[off + IMG_HW];
                val[2] += w * base[off + 2 * IMG_HW];
            }
        }

        // ---- feature sample: 128x128, 32 channels, channels-last ----
        {
            float ix = (gx + 1.f) * 0.5f * 127.f;
            float iy = (gy + 1.f) * 0.5f * 127.f;
            float x0f = floorf(ix), y0f = floorf(iy);
            float x1f = x0f + 1.f, y1f = y0f + 1.f;
            float wx1 = ix - x0f, wx0 = 1.f - wx1;
            float wy1 = iy - y0f, wy0 = 1.f - wy1;
            const float* fb = featsT + (size_t)(v * BATCH + b) * (FT_HW * CF);
            #pragma unroll
            for (int k = 0; k < 4; k++) {
                float xf = (k & 1) ? x1f : x0f;
                float yf = (k >> 1) ? y1f : y0f;
                float w  = ((k & 1) ? wx1 : wx0) * ((k >> 1) ? wy1 : wy0);
                float vd = (xf >= 0.f && xf <= 127.f && yf >= 0.f && yf <= 127.f) ? 1.f : 0.f;
                w *= vd;
                int xi = (int)fminf(fmaxf(xf, 0.f), 127.f);
                int yi = (int)fminf(fmaxf(yf, 0.f), 127.f);
                const float4* p = (const float4*)(fb + (size_t)(yi * 128 + xi) * CF);
                #pragma unroll
                for (int q = 0; q < 8; q++) {
                    float4 f4 = p[q];
                    val[3 + q * 4 + 0] += w * f4.x;
                    val[3 + q * 4 + 1] += w * f4.y;
                    val[3 + q * 4 + 2] += w * f4.z;
                    val[3 + q * 4 + 3] += w * f4.w;
                }
            }
        }

        #pragma unroll
        for (int c = 0; c < NCH; c++) {
            inp[3 + c]  += val[c];
            inp[38 + c] += val[c] * val[c];
        }
    }

    // mean / exp(-var)
    #pragma unroll
    for (int c = 0; c < NCH; c++) {
        float m = inp[3 + c] * 0.2f;
        float q = inp[38 + c] * 0.2f - m * m;
        inp[3 + c]  = m;
        inp[38 + c] = expf(-q);
    }
    // inp[73..95] stay 0 (zero K-padding for the GEMM)

    // pack to bf16 row, 12 x uint4 stores (192B per row, 16B-aligned)
    uint4* arow = (uint4*)(A + (size_t)idx * KA);
    #pragma unroll
    for (int gi = 0; gi < 12; gi++) {
        unsigned int c0 = (unsigned)f2bf(inp[gi * 8 + 0]) | ((unsigned)f2bf(inp[gi * 8 + 1]) << 16);
        unsigned int c1 = (unsigned)f2bf(inp[gi * 8 + 2]) | ((unsigned)f2bf(inp[gi * 8 + 3]) << 16);
        unsigned int c2 = (unsigned)f2bf(inp[gi * 8 + 4]) | ((unsigned)f2bf(inp[gi * 8 + 5]) << 16);
        unsigned int c3 = (unsigned)f2bf(inp[gi * 8 + 6]) | ((unsigned)f2bf(inp[gi * 8 + 7]) << 16);
        arow[gi] = make_uint4(c0, c1, c2, c3);
    }
}

// ---------------------------------------------------------------------------
// Kernel 3: MLP as MFMA GEMM. [256000 x 96]bf16 @ [96 x 256]bf16 -> relu
// -> dot(W2) -> softplus -> alpha, all fused in the epilogue.
// Block = 4 waves, 128 rows (each wave 32 rows x 256 cols).
// W1 staged once per block in LDS in B-fragment order (48KB).
// mfma_f32_16x16x32_bf16: A[m=lane&15][k=quad*8+j], B[k=quad*8+j][n=lane&15],
// C: col=lane&15, row=quad*4+reg  [verified layouts, learn_hip m89]
// ---------------------------------------------------------------------------
__global__ __launch_bounds__(256) void mlp_gemm(
    const unsigned short* __restrict__ A,   // [256000][96] bf16
    const float* __restrict__ W1,    // [73][256]
    const float* __restrict__ b1,    // [256]
    const float* __restrict__ W2,    // [256]
    const float* __restrict__ b2,    // [1]
    float* __restrict__ out)         // [256000]
{
    // Bl[o][n][ju]: packed pairs, element (o*8 + 2ju (+1)) of column n
    __shared__ unsigned int Bl[12 * 256 * 4];   // 48KB
    __shared__ float b1s[HID];
    __shared__ float W2s[HID];

    const int tid = threadIdx.x;
    b1s[tid] = b1[tid];
    W2s[tid] = W2[tid];

    // stage W1 -> bf16 B-fragments (rows >= 73 are zero)
    for (int e = tid; e < 12288; e += 256) {
        int ju = e & 3;
        int n  = (e >> 2) & 255;
        int o  = e >> 10;
        int k0 = o * 8 + ju * 2;
        float f0 = (k0     < 73) ? W1[k0 * 256 + n]       : 0.f;
        float f1 = (k0 + 1 < 73) ? W1[(k0 + 1) * 256 + n] : 0.f;
        Bl[e] = (unsigned)f2bf(f0) | ((unsigned)f2bf(f1) << 16);
    }
    __syncthreads();

    const int w    = tid >> 6;
    const int lane = tid & 63;
    const int col  = lane & 15;
    const int quad = lane >> 4;
    const long rowbase = (long)blockIdx.x * 128 + w * 32;

    f32x4 acc[2][16];
    #pragma unroll
    for (int m = 0; m < 2; m++)
        #pragma unroll
        for (int t = 0; t < 16; t++)
            acc[m][t] = (f32x4){0.f, 0.f, 0.f, 0.f};

    const unsigned short* a0p = A + (rowbase + col) * KA + quad * 8;
    const unsigned short* a1p = a0p + 16 * KA;
    const unsigned int*   bp  = Bl + (quad * 256 + col) * 4;

    #pragma unroll
    for (int s = 0; s < 3; s++) {
        short8 af0 = *(const short8*)(a0p + s * 32);
        short8 af1 = *(const short8*)(a1p + s * 32);
        #pragma unroll
        for (int t = 0; t < 16; t++) {
            short8 bf = *(const short8*)(bp + s * 4096 + t * 64);
            acc[0][t] = __builtin_amdgcn_mfma_f32_16x16x32_bf16(af0, bf, acc[0][t], 0, 0, 0);
            acc[1][t] = __builtin_amdgcn_mfma_f32_16x16x32_bf16(af1, bf, acc[1][t], 0, 0, 0);
        }
    }

    // epilogue: +b1, relu, dot with W2 (partial per lane over its 16 cols)
    float pm[2][4] = {{0.f, 0.f, 0.f, 0.f}, {0.f, 0.f, 0.f, 0.f}};
    #pragma unroll
    for (int t = 0; t < 16; t++) {
        float b1v = b1s[t * 16 + col];
        float w2v = W2s[t * 16 + col];
        #pragma unroll
        for (int m = 0; m < 2; m++)
            #pragma unroll
            for (int r = 0; r < 4; r++) {
                float h = fmaxf(acc[m][t][r] + b1v, 0.f);
                pm[m][r] += h * w2v;
            }
    }
    // reduce over the 16 cols (lanes quad*16 .. quad*16+15)
    #pragma unroll
    for (int m = 0; m < 2; m++)
        #pragma unroll
        for (int r = 0; r < 4; r++) {
            float p = pm[m][r];
            p += __shfl_xor(p, 1);
            p += __shfl_xor(p, 2);
            p += __shfl_xor(p, 4);
            p += __shfl_xor(p, 8);
            pm[m][r] = p;
        }

    if (col == 0) {
        float b2v = b2[0];
        #pragma unroll
        for (int m = 0; m < 2; m++)
            #pragma unroll
            for (int r = 0; r < 4; r++) {
                float x  = pm[m][r] + b2v;
                float sp = fmaxf(x, 0.f) + log1pf(expf(-fabsf(x)));  // softplus
                float alpha = -expm1f(-sp);                          // 1 - exp(-sp)
                out[rowbase + m * 16 + quad * 4 + r] = alpha;
            }
    }
}

extern "C" void kernel_launch(void* const* d_in, const int* in_sizes, int n_in,
                              void* d_out, int out_size, void* d_ws, size_t ws_size,
                              hipStream_t stream) {
    const float* imgs   = (const float*)d_in[0];
    const float* feats  = (const float*)d_in[1];
    const float* grid   = (const float*)d_in[2];
    const float* points = (const float*)d_in[3];
    const float* W1     = (const float*)d_in[4];
    const float* b1     = (const float*)d_in[5];
    const float* W2     = (const float*)d_in[6];
    const float* b2     = (const float*)d_in[7];
    float* out = (float*)d_out;

    // workspace layout: featsT (41.94 MB) | A (49.15 MB)
    float* featsT = (float*)d_ws;
    unsigned short* Abuf =
        (unsigned short*)((char*)d_ws + (size_t)NVIEW * BATCH * CF * FT_HW * 4);

    feats_transpose<<<dim3(2560), dim3(256), 0, stream>>>(feats, (float4*)featsT);
    gather_features<<<dim3(1000), dim3(256), 0, stream>>>(
        imgs, featsT, grid, points, Abuf);
    mlp_gemm<<<dim3(2000), dim3(256), 0, stream>>>(
        Abuf, W1, b1, W2, b2, out);
}

// Round 4
// 290.762 us; speedup vs baseline: 2.2688x; 1.4732x over previous
//
#include <hip/hip_runtime.h>

// Problem constants (from reference; all fp32 I/O)
#define NVIEW 5
#define BATCH 2
#define NB    128000          // NBINS = 80*80*20
#define CI    3
#define CF    32
#define NCH   35              // CI + CF
#define HID   256
#define KA    96              // padded K for the MLP GEMM (73 -> 96 = 3*32)
#define IMG_HW 262144         // 512*512
#define FT_HW  16384          // 128*128

typedef __attribute__((ext_vector_type(8))) short short8;   // 8 bf16 (4 VGPRs)
typedef __attribute__((ext_vector_type(4))) float f32x4;    // MFMA accumulator

__device__ __forceinline__ unsigned int f2bf(float f) {
    unsigned int u = __float_as_uint(f);
    return (u + 0x7fffu + ((u >> 16) & 1u)) >> 16;   // RTNE, returns low 16 bits
}
__device__ __forceinline__ float b2f_lo(unsigned int u) { return __uint_as_float(u << 16); }
__device__ __forceinline__ float b2f_hi(unsigned int u) { return __uint_as_float(u & 0xffff0000u); }

// ---------------------------------------------------------------------------
// Kernel 1a: repack imgs [V][B][3][512][512] fp32 -> [V][512][512][8] bf16
// pixel layout: b0c0,b0c1,b0c2,0, b1c0,b1c1,b1c2,0  (16B -> one uint4 store).
// Reads coalesced per plane, writes fully coalesced.
// ---------------------------------------------------------------------------
__global__ __launch_bounds__(256) void repack_imgs(
    const float* __restrict__ imgs, uint4* __restrict__ outp)
{
    int gid = blockIdx.x * 256 + threadIdx.x;   // 1,310,720
    int v  = gid >> 18;
    int px = gid & (IMG_HW - 1);
    const float* base = imgs + (size_t)v * 6 * IMG_HW + px;
    uint4 o;
    o.x = f2bf(base[0 * IMG_HW]) | (f2bf(base[1 * IMG_HW]) << 16);
    o.y = f2bf(base[2 * IMG_HW]);
    o.z = f2bf(base[3 * IMG_HW]) | (f2bf(base[4 * IMG_HW]) << 16);
    o.w = f2bf(base[5 * IMG_HW]);
    outp[gid] = o;
}

// ---------------------------------------------------------------------------
// Kernel 1b: repack feats [V][B][32][128][128] fp32 -> [V][128][128][B][32] bf16
// One thread per (v, pixel): 64 plane-coalesced reads, 8 uint4 stores (128B).
// ---------------------------------------------------------------------------
__global__ __launch_bounds__(256) void repack_feats(
    const float* __restrict__ f, uint4* __restrict__ outp)
{
    int gid = blockIdx.x * 256 + threadIdx.x;   // 81,920
    int v   = gid >> 14;
    int pix = gid & (FT_HW - 1);
    const float* base = f + (size_t)v * 2 * CF * FT_HW + pix;
    #pragma unroll
    for (int g = 0; g < 8; g++) {               // g = b*4 + quad
        int c0 = g * 8;                         // plane index = b*32 + ch
        uint4 o;
        o.x = f2bf(base[(size_t)(c0 + 0) * FT_HW]) | (f2bf(base[(size_t)(c0 + 1) * FT_HW]) << 16);
        o.y = f2bf(base[(size_t)(c0 + 2) * FT_HW]) | (f2bf(base[(size_t)(c0 + 3) * FT_HW]) << 16);
        o.z = f2bf(base[(size_t)(c0 + 4) * FT_HW]) | (f2bf(base[(size_t)(c0 + 5) * FT_HW]) << 16);
        o.w = f2bf(base[(size_t)(c0 + 6) * FT_HW]) | (f2bf(base[(size_t)(c0 + 7) * FT_HW]) << 16);
        outp[(size_t)gid * 8 + g] = o;
    }
}

// ---------------------------------------------------------------------------
// Kernel 2: gather (bilinear, 5 views) -> mean / exp(-var) -> bf16 feature
// rows [2*NB][96]. Thread gid = 2n + b: lane pairs share identical sample
// coords and split the same 128B (feat) / 16B (img) blocks -> merged requests.
// Per-view hot set = 2MB feat + 4MB img (both batches) -> mostly L2-resident.
// ---------------------------------------------------------------------------
__global__ __launch_bounds__(256) void gather_features(
    const unsigned short* __restrict__ imgsP,   // [V][512][512][8] bf16
    const unsigned short* __restrict__ featsP,  // [V][128][128][2][32] bf16
    const float* __restrict__ grid,             // [V][NB][2]
    const float* __restrict__ points,           // [NB][3]
    unsigned short* __restrict__ A)             // [2*NB][96] bf16, row gid=2n+b
{
    const int gid = blockIdx.x * 256 + threadIdx.x;   // [0, 256000)
    const int n   = gid >> 1;
    const int b   = gid & 1;

    float inp[KA];
    #pragma unroll
    for (int i = 0; i < KA; i++) inp[i] = 0.f;
    inp[0] = points[n * 3 + 0];
    inp[1] = points[n * 3 + 1];
    inp[2] = points[n * 3 + 2];
    // inp[3+c] accumulates sum_v, inp[38+c] accumulates sum_v^2

    #pragma unroll
    for (int v = 0; v < NVIEW; v++) {
        const float2 g = ((const float2*)grid)[v * NB + n];
        float gx = g.x;
        float gy = g.y;

        float val[NCH];
        #pragma unroll
        for (int c = 0; c < NCH; c++) val[c] = 0.f;

        // ---- image sample: 512x512, interleaved bf16, 8B per corner ----
        {
            float ix = (gx + 1.f) * 0.5f * 511.f;
            float iy = (gy + 1.f) * 0.5f * 511.f;
            float x0f = floorf(ix), y0f = floorf(iy);
            float x1f = x0f + 1.f, y1f = y0f + 1.f;
            float wx1 = ix - x0f, wx0 = 1.f - wx1;
            float wy1 = iy - y0f, wy0 = 1.f - wy1;
            const unsigned short* base = imgsP + ((size_t)v * IMG_HW) * 8 + b * 4;
            #pragma unroll
            for (int k = 0; k < 4; k++) {
                float xf = (k & 1) ? x1f : x0f;
                float yf = (k >> 1) ? y1f : y0f;
                float w  = ((k & 1) ? wx1 : wx0) * ((k >> 1) ? wy1 : wy0);
                float vd = (xf >= 0.f && xf <= 511.f && yf >= 0.f && yf <= 511.f) ? 1.f : 0.f;
                w *= vd;
                int xi = (int)fminf(fmaxf(xf, 0.f), 511.f);
                int yi = (int)fminf(fmaxf(yf, 0.f), 511.f);
                uint2 iv = *(const uint2*)(base + (size_t)(yi * 512 + xi) * 8);
                val[0] += w * b2f_lo(iv.x);
                val[1] += w * b2f_hi(iv.x);
                val[2] += w * b2f_lo(iv.y);
            }
        }

        // ---- feature sample: 128x128, interleaved bf16, 64B per corner ----
        {
            float ix = (gx + 1.f) * 0.5f * 127.f;
            float iy = (gy + 1.f) * 0.5f * 127.f;
            float x0f = floorf(ix), y0f = floorf(iy);
            float x1f = x0f + 1.f, y1f = y0f + 1.f;
            float wx1 = ix - x0f, wx0 = 1.f - wx1;
            float wy1 = iy - y0f, wy0 = 1.f - wy1;
            const unsigned short* fb = featsP + ((size_t)v * FT_HW) * 64 + b * 32;
            #pragma unroll
            for (int k = 0; k < 4; k++) {
                float xf = (k & 1) ? x1f : x0f;
                float yf = (k >> 1) ? y1f : y0f;
                float w  = ((k & 1) ? wx1 : wx0) * ((k >> 1) ? wy1 : wy0);
                float vd = (xf >= 0.f && xf <= 127.f && yf >= 0.f && yf <= 127.f) ? 1.f : 0.f;
                w *= vd;
                int xi = (int)fminf(fmaxf(xf, 0.f), 127.f);
                int yi = (int)fminf(fmaxf(yf, 0.f), 127.f);
                const uint4* p = (const uint4*)(fb + (size_t)(yi * 128 + xi) * 64);
                #pragma unroll
                for (int q = 0; q < 4; q++) {
                    uint4 f4 = p[q];
                    val[3 + q * 8 + 0] += w * b2f_lo(f4.x);
                    val[3 + q * 8 + 1] += w * b2f_hi(f4.x);
                    val[3 + q * 8 + 2] += w * b2f_lo(f4.y);
                    val[3 + q * 8 + 3] += w * b2f_hi(f4.y);
                    val[3 + q * 8 + 4] += w * b2f_lo(f4.z);
                    val[3 + q * 8 + 5] += w * b2f_hi(f4.z);
                    val[3 + q * 8 + 6] += w * b2f_lo(f4.w);
                    val[3 + q * 8 + 7] += w * b2f_hi(f4.w);
                }
            }
        }

        #pragma unroll
        for (int c = 0; c < NCH; c++) {
            inp[3 + c]  += val[c];
            inp[38 + c] += val[c] * val[c];
        }
    }

    // mean / exp(-var)
    #pragma unroll
    for (int c = 0; c < NCH; c++) {
        float m = inp[3 + c] * 0.2f;
        float q = inp[38 + c] * 0.2f - m * m;
        inp[3 + c]  = m;
        inp[38 + c] = expf(-q);
    }
    // inp[73..95] stay 0 (zero K-padding for the GEMM)

    // pack to bf16 row, 12 x uint4 stores (192B per row, 16B-aligned)
    uint4* arow = (uint4*)(A + (size_t)gid * KA);
    #pragma unroll
    for (int gi = 0; gi < 12; gi++) {
        unsigned int c0 = f2bf(inp[gi * 8 + 0]) | (f2bf(inp[gi * 8 + 1]) << 16);
        unsigned int c1 = f2bf(inp[gi * 8 + 2]) | (f2bf(inp[gi * 8 + 3]) << 16);
        unsigned int c2 = f2bf(inp[gi * 8 + 4]) | (f2bf(inp[gi * 8 + 5]) << 16);
        unsigned int c3 = f2bf(inp[gi * 8 + 6]) | (f2bf(inp[gi * 8 + 7]) << 16);
        arow[gi] = make_uint4(c0, c1, c2, c3);
    }
}

// ---------------------------------------------------------------------------
// Kernel 3: MLP as MFMA GEMM. [256000 x 96]bf16 @ [96 x 256]bf16 -> relu
// -> dot(W2) -> softplus -> alpha, fused epilogue. Row gid = 2n + b, so the
// final store remaps to out[b*NB + n].
// mfma_f32_16x16x32_bf16: A[m=lane&15][k=quad*8+j], B[k=quad*8+j][n=lane&15],
// C: col=lane&15, row=quad*4+reg  [verified layouts, learn_hip m89]
// ---------------------------------------------------------------------------
__global__ __launch_bounds__(256) void mlp_gemm(
    const unsigned short* __restrict__ A,   // [256000][96] bf16
    const float* __restrict__ W1,    // [73][256]
    const float* __restrict__ b1,    // [256]
    const float* __restrict__ W2,    // [256]
    const float* __restrict__ b2,    // [1]
    float* __restrict__ out)         // [256000] = [B][NB]
{
    // Bl[o][n][ju]: packed pairs, element (o*8 + 2ju (+1)) of column n
    __shared__ unsigned int Bl[12 * 256 * 4];   // 48KB
    __shared__ float b1s[HID];
    __shared__ float W2s[HID];

    const int tid = threadIdx.x;
    b1s[tid] = b1[tid];
    W2s[tid] = W2[tid];

    // stage W1 -> bf16 B-fragments (rows >= 73 are zero)
    for (int e = tid; e < 12288; e += 256) {
        int ju = e & 3;
        int n  = (e >> 2) & 255;
        int o  = e >> 10;
        int k0 = o * 8 + ju * 2;
        float f0 = (k0     < 73) ? W1[k0 * 256 + n]       : 0.f;
        float f1 = (k0 + 1 < 73) ? W1[(k0 + 1) * 256 + n] : 0.f;
        Bl[e] = f2bf(f0) | (f2bf(f1) << 16);
    }
    __syncthreads();

    const int w    = tid >> 6;
    const int lane = tid & 63;
    const int col  = lane & 15;
    const int quad = lane >> 4;
    const long rowbase = (long)blockIdx.x * 128 + w * 32;

    f32x4 acc[2][16];
    #pragma unroll
    for (int m = 0; m < 2; m++)
        #pragma unroll
        for (int t = 0; t < 16; t++)
            acc[m][t] = (f32x4){0.f, 0.f, 0.f, 0.f};

    const unsigned short* a0p = A + (rowbase + col) * KA + quad * 8;
    const unsigned short* a1p = a0p + 16 * KA;
    const unsigned int*   bp  = Bl + (quad * 256 + col) * 4;

    #pragma unroll
    for (int s = 0; s < 3; s++) {
        short8 af0 = *(const short8*)(a0p + s * 32);
        short8 af1 = *(const short8*)(a1p + s * 32);
        #pragma unroll
        for (int t = 0; t < 16; t++) {
            short8 bf = *(const short8*)(bp + s * 4096 + t * 64);
            acc[0][t] = __builtin_amdgcn_mfma_f32_16x16x32_bf16(af0, bf, acc[0][t], 0, 0, 0);
            acc[1][t] = __builtin_amdgcn_mfma_f32_16x16x32_bf16(af1, bf, acc[1][t], 0, 0, 0);
        }
    }

    // epilogue: +b1, relu, dot with W2 (partial per lane over its 16 cols)
    float pm[2][4] = {{0.f, 0.f, 0.f, 0.f}, {0.f, 0.f, 0.f, 0.f}};
    #pragma unroll
    for (int t = 0; t < 16; t++) {
        float b1v = b1s[t * 16 + col];
        float w2v = W2s[t * 16 + col];
        #pragma unroll
        for (int m = 0; m < 2; m++)
            #pragma unroll
            for (int r = 0; r < 4; r++) {
                float h = fmaxf(acc[m][t][r] + b1v, 0.f);
                pm[m][r] += h * w2v;
            }
    }
    // reduce over the 16 cols (lanes quad*16 .. quad*16+15)
    #pragma unroll
    for (int m = 0; m < 2; m++)
        #pragma unroll
        for (int r = 0; r < 4; r++) {
            float p = pm[m][r];
            p += __shfl_xor(p, 1);
            p += __shfl_xor(p, 2);
            p += __shfl_xor(p, 4);
            p += __shfl_xor(p, 8);
            pm[m][r] = p;
        }

    if (col == 0) {
        float b2v = b2[0];
        #pragma unroll
        for (int m = 0; m < 2; m++)
            #pragma unroll
            for (int r = 0; r < 4; r++) {
                float x  = pm[m][r] + b2v;
                float sp = fmaxf(x, 0.f) + log1pf(expf(-fabsf(x)));  // softplus
                float alpha = -expm1f(-sp);                          // 1 - exp(-sp)
                long row = rowbase + m * 16 + quad * 4 + r;          // = 2n + b
                out[(row & 1) * (long)NB + (row >> 1)] = alpha;
            }
    }
}

extern "C" void kernel_launch(void* const* d_in, const int* in_sizes, int n_in,
                              void* d_out, int out_size, void* d_ws, size_t ws_size,
                              hipStream_t stream) {
    const float* imgs   = (const float*)d_in[0];
    const float* feats  = (const float*)d_in[1];
    const float* grid   = (const float*)d_in[2];
    const float* points = (const float*)d_in[3];
    const float* W1     = (const float*)d_in[4];
    const float* b1     = (const float*)d_in[5];
    const float* W2     = (const float*)d_in[6];
    const float* b2     = (const float*)d_in[7];
    float* out = (float*)d_out;

    // workspace layout: imgsP 20.97MB | featsP 10.49MB | A 49.15MB
    unsigned short* imgsP  = (unsigned short*)d_ws;
    unsigned short* featsP = imgsP + (size_t)NVIEW * IMG_HW * 8;
    unsigned short* Abuf   = featsP + (size_t)NVIEW * FT_HW * 64;

    repack_imgs<<<dim3(5120), dim3(256), 0, stream>>>(imgs, (uint4*)imgsP);
    repack_feats<<<dim3(320), dim3(256), 0, stream>>>(feats, (uint4*)featsP);
    gather_features<<<dim3(1000), dim3(256), 0, stream>>>(
        imgsP, featsP, grid, points, Abuf);
    mlp_gemm<<<dim3(2000), dim3(256), 0, stream>>>(
        Abuf, W1, b1, W2, b2, out);
}

// Round 5
// 288.589 us; speedup vs baseline: 2.2859x; 1.0075x over previous
//
#include <hip/hip_runtime.h>

// Problem constants (from reference; all fp32 I/O)
#define NVIEW 5
#define NB    128000          // NBINS = 80*80*20
#define CF    32
#define HID   256
#define KA    96              // padded K for the MLP GEMM
#define IMG_HW 262144         // 512*512
#define FT_HW  16384          // 128*128

typedef __attribute__((ext_vector_type(8))) short short8;   // 8 bf16 (4 VGPRs)
typedef __attribute__((ext_vector_type(4))) float f32x4;    // MFMA accumulator

__device__ __forceinline__ unsigned int f2bf(float f) {
    unsigned int u = __float_as_uint(f);
    return (u + 0x7fffu + ((u >> 16) & 1u)) >> 16;   // RTNE, low 16 bits
}
__device__ __forceinline__ unsigned int pk(float a, float b) {
    return f2bf(a) | (f2bf(b) << 16);
}
__device__ __forceinline__ float b2f_lo(unsigned int u) { return __uint_as_float(u << 16); }
__device__ __forceinline__ float b2f_hi(unsigned int u) { return __uint_as_float(u & 0xffff0000u); }

// A-row layout (96 shorts, per (point,b) row = 2n+b), built by lane halves:
//  slice0 (shorts 0..47, half0):  pts(3) mi(3) mf ch0..15 (16) | vi(3) pad(1) vf ch0..15 (16) pad(6)
//  slice1 (shorts 48..95, half1): mf ch16..31 (16) vf ch16..31 (16) pad(16)
// mapk: A-row index k -> original W1 row i (73-dim input), -1 = zero pad.
__device__ __forceinline__ int mapk(int k) {
    if (k < 22) return k;          // pts + mean img + mean feat0..15 (i == k)
    if (k < 25) return k + 16;     // var img (38+c)
    if (k == 25) return -1;
    if (k < 42) return k + 15;     // var feat0..15
    if (k < 48) return -1;
    if (k < 64) return k - 26;     // mean feat16..31
    if (k < 80) return k - 7;      // var feat16..31
    return -1;
}

// ---------------------------------------------------------------------------
// Kernel 1a: repack imgs [V][B][3][512][512] fp32 -> [V][512][512][8] bf16
// pixel layout: b0c0,b0c1,b0c2,0, b1c0,b1c1,b1c2,0  (16B -> one uint4 store).
// ---------------------------------------------------------------------------
__global__ __launch_bounds__(256) void repack_imgs(
    const float* __restrict__ imgs, uint4* __restrict__ outp)
{
    int gid = blockIdx.x * 256 + threadIdx.x;   // 1,310,720
    int v  = gid >> 18;
    int px = gid & (IMG_HW - 1);
    const float* base = imgs + (size_t)v * 6 * IMG_HW + px;
    uint4 o;
    o.x = f2bf(base[0 * IMG_HW]) | (f2bf(base[1 * IMG_HW]) << 16);
    o.y = f2bf(base[2 * IMG_HW]);
    o.z = f2bf(base[3 * IMG_HW]) | (f2bf(base[4 * IMG_HW]) << 16);
    o.w = f2bf(base[5 * IMG_HW]);
    outp[gid] = o;
}

// ---------------------------------------------------------------------------
// Kernel 1b: repack feats [V][B][32][128][128] fp32 -> [V][128][128][B][32]
// bf16 via LDS tile. 1280 blocks x 64 pixels; reads coalesced per plane
// (64 consecutive fp32 per wave-instruction), writes consecutive uint4s.
// ---------------------------------------------------------------------------
__global__ __launch_bounds__(256) void repack_feats(
    const float* __restrict__ f, uint4* __restrict__ outp)
{
    __shared__ unsigned short tile[64][65];     // 64 planes x 64 pixels (+pad)
    const int t = threadIdx.x;
    const int pixbase = blockIdx.x * 64;        // linear over v*16384+rem
    const int v   = pixbase >> 14;
    const int rem = pixbase & 16383;

    {
        const int p = t & 63;
        const int s = t >> 6;
        #pragma unroll
        for (int it = 0; it < 16; it++) {
            int plane = it * 4 + s;             // = b*32 + ch
            tile[plane][p] =
                (unsigned short)f2bf(f[((size_t)v * 64 + plane) * FT_HW + rem + p]);
        }
    }
    __syncthreads();
    {
        const int q = t & 7;                    // uint4 index within pixel
        #pragma unroll
        for (int it = 0; it < 2; it++) {
            int p = it * 32 + (t >> 3);
            uint4 o;
            o.x = (unsigned)tile[q * 8 + 0][p] | ((unsigned)tile[q * 8 + 1][p] << 16);
            o.y = (unsigned)tile[q * 8 + 2][p] | ((unsigned)tile[q * 8 + 3][p] << 16);
            o.z = (unsigned)tile[q * 8 + 4][p] | ((unsigned)tile[q * 8 + 5][p] << 16);
            o.w = (unsigned)tile[q * 8 + 6][p] | ((unsigned)tile[q * 8 + 7][p] << 16);
            outp[(size_t)(pixbase + p) * 8 + q] = o;
        }
    }
}

// ---------------------------------------------------------------------------
// Kernel 2: gather. 4 lanes per point: gid = 4n + 2b + half.
//  half0: img (3ch) + feat ch0..15 ; half1: feat ch16..31.
// The 4 lanes of a point read one contiguous 128B feature block per corner.
// Each lane writes its contiguous 96B half-row of A (6 uint4 stores).
// ---------------------------------------------------------------------------
__global__ __launch_bounds__(256) void gather_features(
    const unsigned short* __restrict__ imgsP,   // [V][512][512][8] bf16
    const unsigned short* __restrict__ featsP,  // [V][128][128][2][32] bf16
    const float* __restrict__ grid,             // [V][NB][2]
    const float* __restrict__ points,           // [NB][3]
    unsigned short* __restrict__ A)             // [2*NB][96] bf16
{
    const int gid  = blockIdx.x * 256 + threadIdx.x;   // [0, 512000)
    const int n    = gid >> 2;
    const int b    = (gid >> 1) & 1;
    const int half = gid & 1;

    float sumf[16], ssqf[16];
    #pragma unroll
    for (int c = 0; c < 16; c++) { sumf[c] = 0.f; ssqf[c] = 0.f; }
    float si0 = 0.f, si1 = 0.f, si2 = 0.f;      // img sums (half0 only)
    float qi0 = 0.f, qi1 = 0.f, qi2 = 0.f;      // img sumsq
    float p0 = 0.f, p1 = 0.f, p2 = 0.f;
    if (half == 0) {
        p0 = points[n * 3 + 0];
        p1 = points[n * 3 + 1];
        p2 = points[n * 3 + 2];
    }

    #pragma unroll
    for (int v = 0; v < NVIEW; v++) {
        const float2 g = ((const float2*)grid)[v * NB + n];
        const float gx = g.x, gy = g.y;

        // ---- image sample (half0 lanes only): 8B per corner ----
        float vi0 = 0.f, vi1 = 0.f, vi2 = 0.f;
        if (half == 0) {
            float ix = (gx + 1.f) * 0.5f * 511.f;
            float iy = (gy + 1.f) * 0.5f * 511.f;
            float x0f = floorf(ix), y0f = floorf(iy);
            float x1f = x0f + 1.f, y1f = y0f + 1.f;
            float wx1 = ix - x0f, wx0 = 1.f - wx1;
            float wy1 = iy - y0f, wy0 = 1.f - wy1;
            const unsigned short* base = imgsP + ((size_t)v * IMG_HW) * 8 + b * 4;
            #pragma unroll
            for (int k = 0; k < 4; k++) {
                float xf = (k & 1) ? x1f : x0f;
                float yf = (k >> 1) ? y1f : y0f;
                float w  = ((k & 1) ? wx1 : wx0) * ((k >> 1) ? wy1 : wy0);
                float vd = (xf >= 0.f && xf <= 511.f && yf >= 0.f && yf <= 511.f) ? 1.f : 0.f;
                w *= vd;
                int xi = (int)fminf(fmaxf(xf, 0.f), 511.f);
                int yi = (int)fminf(fmaxf(yf, 0.f), 511.f);
                uint2 iv = *(const uint2*)(base + (size_t)(yi * 512 + xi) * 8);
                vi0 += w * b2f_lo(iv.x);
                vi1 += w * b2f_hi(iv.x);
                vi2 += w * b2f_lo(iv.y);
            }
            si0 += vi0; qi0 += vi0 * vi0;
            si1 += vi1; qi1 += vi1 * vi1;
            si2 += vi2; qi2 += vi2 * vi2;
        }

        // ---- feature sample: 32B per corner per lane (contiguous x4 lanes) ----
        {
            float ix = (gx + 1.f) * 0.5f * 127.f;
            float iy = (gy + 1.f) * 0.5f * 127.f;
            float x0f = floorf(ix), y0f = floorf(iy);
            float x1f = x0f + 1.f, y1f = y0f + 1.f;
            float wx1 = ix - x0f, wx0 = 1.f - wx1;
            float wy1 = iy - y0f, wy0 = 1.f - wy1;
            const unsigned short* fb =
                featsP + ((size_t)v * FT_HW) * 64 + b * 32 + half * 16;
            float val[16];
            #pragma unroll
            for (int c = 0; c < 16; c++) val[c] = 0.f;
            #pragma unroll
            for (int k = 0; k < 4; k++) {
                float xf = (k & 1) ? x1f : x0f;
                float yf = (k >> 1) ? y1f : y0f;
                float w  = ((k & 1) ? wx1 : wx0) * ((k >> 1) ? wy1 : wy0);
                float vd = (xf >= 0.f && xf <= 127.f && yf >= 0.f && yf <= 127.f) ? 1.f : 0.f;
                w *= vd;
                int xi = (int)fminf(fmaxf(xf, 0.f), 127.f);
                int yi = (int)fminf(fmaxf(yf, 0.f), 127.f);
                const uint4* p = (const uint4*)(fb + (size_t)(yi * 128 + xi) * 64);
                #pragma unroll
                for (int q = 0; q < 2; q++) {
                    uint4 f4 = p[q];
                    val[q * 8 + 0] += w * b2f_lo(f4.x);
                    val[q * 8 + 1] += w * b2f_hi(f4.x);
                    val[q * 8 + 2] += w * b2f_lo(f4.y);
                    val[q * 8 + 3] += w * b2f_hi(f4.y);
                    val[q * 8 + 4] += w * b2f_lo(f4.z);
                    val[q * 8 + 5] += w * b2f_hi(f4.z);
                    val[q * 8 + 6] += w * b2f_lo(f4.w);
                    val[q * 8 + 7] += w * b2f_hi(f4.w);
                }
            }
            #pragma unroll
            for (int c = 0; c < 16; c++) {
                sumf[c] += val[c];
                ssqf[c] += val[c] * val[c];
            }
        }
    }

    // finalize: mean / exp(-var)  (in place)
    #pragma unroll
    for (int c = 0; c < 16; c++) {
        float m = sumf[c] * 0.2f;
        float q = ssqf[c] * 0.2f - m * m;
        sumf[c] = m;
        ssqf[c] = expf(-q);
    }
    float mi0 = si0 * 0.2f, mi1 = si1 * 0.2f, mi2 = si2 * 0.2f;
    float ei0 = expf(-(qi0 * 0.2f - mi0 * mi0));
    float ei1 = expf(-(qi1 * 0.2f - mi1 * mi1));
    float ei2 = expf(-(qi2 * 0.2f - mi2 * mi2));

    unsigned int u[24];
    if (half == 0) {
        u[0] = pk(p0, p1);
        u[1] = pk(p2, mi0);
        u[2] = pk(mi1, mi2);
        #pragma unroll
        for (int j = 0; j < 8; j++) u[3 + j] = pk(sumf[2 * j], sumf[2 * j + 1]);
        u[11] = pk(ei0, ei1);
        u[12] = pk(ei2, 0.f);
        #pragma unroll
        for (int j = 0; j < 8; j++) u[13 + j] = pk(ssqf[2 * j], ssqf[2 * j + 1]);
        u[21] = 0u; u[22] = 0u; u[23] = 0u;
    } else {
        #pragma unroll
        for (int j = 0; j < 8; j++) u[j]     = pk(sumf[2 * j], sumf[2 * j + 1]);
        #pragma unroll
        for (int j = 0; j < 8; j++) u[8 + j] = pk(ssqf[2 * j], ssqf[2 * j + 1]);
        #pragma unroll
        for (int j = 16; j < 24; j++) u[j] = 0u;
    }

    // row = 2n + b = gid>>1 ; each lane stores its contiguous 96B half
    uint4* arow = (uint4*)(A + (size_t)(gid >> 1) * KA + half * 48);
    #pragma unroll
    for (int i = 0; i < 6; i++)
        arow[i] = make_uint4(u[4 * i], u[4 * i + 1], u[4 * i + 2], u[4 * i + 3]);
}

// ---------------------------------------------------------------------------
// Kernel 3: MLP as MFMA GEMM. [256000 x 96]bf16 @ [96 x 256]bf16 -> relu
// -> dot(W2) -> softplus -> alpha, fused epilogue. Row gid = 2n + b.
// W1 rows permuted per mapk to match the A-row layout.
// mfma_f32_16x16x32_bf16: A[m=lane&15][k=quad*8+j], B[k=quad*8+j][n=lane&15],
// C: col=lane&15, row=quad*4+reg  [verified layouts, learn_hip m89]
// ---------------------------------------------------------------------------
__global__ __launch_bounds__(256) void mlp_gemm(
    const unsigned short* __restrict__ A,   // [256000][96] bf16
    const float* __restrict__ W1,    // [73][256]
    const float* __restrict__ b1,    // [256]
    const float* __restrict__ W2,    // [256]
    const float* __restrict__ b2,    // [1]
    float* __restrict__ out)         // [256000] = [B][NB]
{
    // Bl[o][n][ju]: packed pairs, element (o*8 + 2ju (+1)) of column n
    __shared__ unsigned int Bl[12 * 256 * 4];   // 48KB
    __shared__ float b1s[HID];
    __shared__ float W2s[HID];

    const int tid = threadIdx.x;
    b1s[tid] = b1[tid];
    W2s[tid] = W2[tid];

    // stage W1 -> bf16 B-fragments in permuted K order
    for (int e = tid; e < 12288; e += 256) {
        int ju = e & 3;
        int nn = (e >> 2) & 255;
        int o  = e >> 10;
        int k0 = o * 8 + ju * 2;
        int i0 = mapk(k0), i1 = mapk(k0 + 1);
        float f0 = (i0 >= 0) ? W1[i0 * 256 + nn] : 0.f;
        float f1 = (i1 >= 0) ? W1[i1 * 256 + nn] : 0.f;
        Bl[e] = pk(f0, f1);
    }
    __syncthreads();

    const int w    = tid >> 6;
    const int lane = tid & 63;
    const int col  = lane & 15;
    const int quad = lane >> 4;
    const long rowbase = (long)blockIdx.x * 128 + w * 32;

    f32x4 acc[2][16];
    #pragma unroll
    for (int m = 0; m < 2; m++)
        #pragma unroll
        for (int t = 0; t < 16; t++)
            acc[m][t] = (f32x4){0.f, 0.f, 0.f, 0.f};

    const unsigned short* a0p = A + (rowbase + col) * KA + quad * 8;
    const unsigned short* a1p = a0p + 16 * KA;
    const unsigned int*   bp  = Bl + (quad * 256 + col) * 4;

    #pragma unroll
    for (int s = 0; s < 3; s++) {
        short8 af0 = *(const short8*)(a0p + s * 32);
        short8 af1 = *(const short8*)(a1p + s * 32);
        #pragma unroll
        for (int t = 0; t < 16; t++) {
            short8 bf = *(const short8*)(bp + s * 4096 + t * 64);
            acc[0][t] = __builtin_amdgcn_mfma_f32_16x16x32_bf16(af0, bf, acc[0][t], 0, 0, 0);
            acc[1][t] = __builtin_amdgcn_mfma_f32_16x16x32_bf16(af1, bf, acc[1][t], 0, 0, 0);
        }
    }

    // epilogue: +b1, relu, dot with W2 (partial per lane over its 16 cols)
    float pm[2][4] = {{0.f, 0.f, 0.f, 0.f}, {0.f, 0.f, 0.f, 0.f}};
    #pragma unroll
    for (int t = 0; t < 16; t++) {
        float b1v = b1s[t * 16 + col];
        float w2v = W2s[t * 16 + col];
        #pragma unroll
        for (int m = 0; m < 2; m++)
            #pragma unroll
            for (int r = 0; r < 4; r++) {
                float h = fmaxf(acc[m][t][r] + b1v, 0.f);
                pm[m][r] += h * w2v;
            }
    }
    #pragma unroll
    for (int m = 0; m < 2; m++)
        #pragma unroll
        for (int r = 0; r < 4; r++) {
            float p = pm[m][r];
            p += __shfl_xor(p, 1);
            p += __shfl_xor(p, 2);
            p += __shfl_xor(p, 4);
            p += __shfl_xor(p, 8);
            pm[m][r] = p;
        }

    if (col == 0) {
        float b2v = b2[0];
        #pragma unroll
        for (int m = 0; m < 2; m++)
            #pragma unroll
            for (int r = 0; r < 4; r++) {
                float x  = pm[m][r] + b2v;
                float sp = fmaxf(x, 0.f) + log1pf(expf(-fabsf(x)));  // softplus
                float alpha = -expm1f(-sp);                          // 1 - exp(-sp)
                long row = rowbase + m * 16 + quad * 4 + r;          // = 2n + b
                out[(row & 1) * (long)NB + (row >> 1)] = alpha;
            }
    }
}

extern "C" void kernel_launch(void* const* d_in, const int* in_sizes, int n_in,
                              void* d_out, int out_size, void* d_ws, size_t ws_size,
                              hipStream_t stream) {
    const float* imgs   = (const float*)d_in[0];
    const float* feats  = (const float*)d_in[1];
    const float* grid   = (const float*)d_in[2];
    const float* points = (const float*)d_in[3];
    const float* W1     = (const float*)d_in[4];
    const float* b1     = (const float*)d_in[5];
    const float* W2     = (const float*)d_in[6];
    const float* b2     = (const float*)d_in[7];
    float* out = (float*)d_out;

    // workspace layout: imgsP 20.97MB | featsP 10.49MB | A 49.15MB
    unsigned short* imgsP  = (unsigned short*)d_ws;
    unsigned short* featsP = imgsP + (size_t)NVIEW * IMG_HW * 8;
    unsigned short* Abuf   = featsP + (size_t)NVIEW * FT_HW * 64;

    repack_imgs<<<dim3(5120), dim3(256), 0, stream>>>(imgs, (uint4*)imgsP);
    repack_feats<<<dim3(1280), dim3(256), 0, stream>>>(feats, (uint4*)featsP);
    gather_features<<<dim3(2000), dim3(256), 0, stream>>>(
        imgsP, featsP, grid, points, Abuf);
    mlp_gemm<<<dim3(2000), dim3(256), 0, stream>>>(
        Abuf, W1, b1, W2, b2, out);
}

// Round 6
// 232.990 us; speedup vs baseline: 2.8313x; 1.2386x over previous
//
#include <hip/hip_runtime.h>

// Problem constants (from reference; all fp32 I/O)
#define NVIEW 5
#define NB    128000          // NBINS = 80*80*20
#define CF    32
#define HID   256
#define KA    96              // padded K for the MLP GEMM
#define IMG_HW 262144         // 512*512
#define FT_HW  16384          // 128*128
#define NTILE 2000            // 256000 rows / 128 rows per tile
#define GEMM_BLOCKS 768

typedef __attribute__((ext_vector_type(8))) short short8;   // 8 bf16 (4 VGPRs)
typedef __attribute__((ext_vector_type(4))) float f32x4;    // MFMA accumulator

__device__ __forceinline__ unsigned int f2bf(float f) {
    unsigned int u = __float_as_uint(f);
    return (u + 0x7fffu + ((u >> 16) & 1u)) >> 16;   // RTNE, low 16 bits
}
__device__ __forceinline__ unsigned int pk(float a, float b) {
    return f2bf(a) | (f2bf(b) << 16);
}
__device__ __forceinline__ float b2f_lo(unsigned int u) { return __uint_as_float(u << 16); }
__device__ __forceinline__ float b2f_hi(unsigned int u) { return __uint_as_float(u & 0xffff0000u); }

// A-row layout (96 shorts, per (point,b) row = 2n+b), built by lane halves:
//  slice0 (shorts 0..47, half0):  pts(3) mi(3) mf ch0..15 (16) | vi(3) pad(1) vf ch0..15 (16) pad(6)
//  slice1 (shorts 48..95, half1): mf ch16..31 (16) vf ch16..31 (16) pad(16)
// mapk: A-row index k -> original W1 row i (73-dim input), -1 = zero pad.
__device__ __forceinline__ int mapk(int k) {
    if (k < 22) return k;          // pts + mean img + mean feat0..15 (i == k)
    if (k < 25) return k + 16;     // var img (38+c)
    if (k == 25) return -1;
    if (k < 42) return k + 15;     // var feat0..15
    if (k < 48) return -1;
    if (k < 64) return k - 26;     // mean feat16..31
    if (k < 80) return k - 7;      // var feat16..31
    return -1;
}

// ---------------------------------------------------------------------------
// Kernel 1a: repack imgs [V][B][3][512][512] fp32 -> [V][512][512][8] bf16
// pixel layout: b0c0,b0c1,b0c2,0, b1c0,b1c1,b1c2,0  (16B -> one uint4 store).
// ---------------------------------------------------------------------------
__global__ __launch_bounds__(256) void repack_imgs(
    const float* __restrict__ imgs, uint4* __restrict__ outp)
{
    int gid = blockIdx.x * 256 + threadIdx.x;   // 1,310,720
    int v  = gid >> 18;
    int px = gid & (IMG_HW - 1);
    const float* base = imgs + (size_t)v * 6 * IMG_HW + px;
    uint4 o;
    o.x = f2bf(base[0 * IMG_HW]) | (f2bf(base[1 * IMG_HW]) << 16);
    o.y = f2bf(base[2 * IMG_HW]);
    o.z = f2bf(base[3 * IMG_HW]) | (f2bf(base[4 * IMG_HW]) << 16);
    o.w = f2bf(base[5 * IMG_HW]);
    outp[gid] = o;
}

// ---------------------------------------------------------------------------
// Kernel 1b: repack feats [V][B][32][128][128] fp32 -> [V][128][128][B][32]
// bf16 via LDS tile. 1280 blocks x 64 pixels.
// ---------------------------------------------------------------------------
__global__ __launch_bounds__(256) void repack_feats(
    const float* __restrict__ f, uint4* __restrict__ outp)
{
    __shared__ unsigned short tile[64][65];     // 64 planes x 64 pixels (+pad)
    const int t = threadIdx.x;
    const int pixbase = blockIdx.x * 64;        // linear over v*16384+rem
    const int v   = pixbase >> 14;
    const int rem = pixbase & 16383;

    {
        const int p = t & 63;
        const int s = t >> 6;
        #pragma unroll
        for (int it = 0; it < 16; it++) {
            int plane = it * 4 + s;             // = b*32 + ch
            tile[plane][p] =
                (unsigned short)f2bf(f[((size_t)v * 64 + plane) * FT_HW + rem + p]);
        }
    }
    __syncthreads();
    {
        const int q = t & 7;                    // uint4 index within pixel
        #pragma unroll
        for (int it = 0; it < 2; it++) {
            int p = it * 32 + (t >> 3);
            uint4 o;
            o.x = (unsigned)tile[q * 8 + 0][p] | ((unsigned)tile[q * 8 + 1][p] << 16);
            o.y = (unsigned)tile[q * 8 + 2][p] | ((unsigned)tile[q * 8 + 3][p] << 16);
            o.z = (unsigned)tile[q * 8 + 4][p] | ((unsigned)tile[q * 8 + 5][p] << 16);
            o.w = (unsigned)tile[q * 8 + 6][p] | ((unsigned)tile[q * 8 + 7][p] << 16);
            outp[(size_t)(pixbase + p) * 8 + q] = o;
        }
    }
}

// ---------------------------------------------------------------------------
// Kernel 2: gather. 4 lanes per point: gid = 4n + 2b + half.
//  half0: img (3ch) + feat ch0..15 ; half1: feat ch16..31.
// ---------------------------------------------------------------------------
__global__ __launch_bounds__(256) void gather_features(
    const unsigned short* __restrict__ imgsP,   // [V][512][512][8] bf16
    const unsigned short* __restrict__ featsP,  // [V][128][128][2][32] bf16
    const float* __restrict__ grid,             // [V][NB][2]
    const float* __restrict__ points,           // [NB][3]
    unsigned short* __restrict__ A)             // [2*NB][96] bf16
{
    const int gid  = blockIdx.x * 256 + threadIdx.x;   // [0, 512000)
    const int n    = gid >> 2;
    const int b    = (gid >> 1) & 1;
    const int half = gid & 1;

    float sumf[16], ssqf[16];
    #pragma unroll
    for (int c = 0; c < 16; c++) { sumf[c] = 0.f; ssqf[c] = 0.f; }
    float si0 = 0.f, si1 = 0.f, si2 = 0.f;      // img sums (half0 only)
    float qi0 = 0.f, qi1 = 0.f, qi2 = 0.f;      // img sumsq
    float p0 = 0.f, p1 = 0.f, p2 = 0.f;
    if (half == 0) {
        p0 = points[n * 3 + 0];
        p1 = points[n * 3 + 1];
        p2 = points[n * 3 + 2];
    }

    #pragma unroll
    for (int v = 0; v < NVIEW; v++) {
        const float2 g = ((const float2*)grid)[v * NB + n];
        const float gx = g.x, gy = g.y;

        // ---- image sample (half0 lanes only): 8B per corner ----
        float vi0 = 0.f, vi1 = 0.f, vi2 = 0.f;
        if (half == 0) {
            float ix = (gx + 1.f) * 0.5f * 511.f;
            float iy = (gy + 1.f) * 0.5f * 511.f;
            float x0f = floorf(ix), y0f = floorf(iy);
            float x1f = x0f + 1.f, y1f = y0f + 1.f;
            float wx1 = ix - x0f, wx0 = 1.f - wx1;
            float wy1 = iy - y0f, wy0 = 1.f - wy1;
            const unsigned short* base = imgsP + ((size_t)v * IMG_HW) * 8 + b * 4;
            #pragma unroll
            for (int k = 0; k < 4; k++) {
                float xf = (k & 1) ? x1f : x0f;
                float yf = (k >> 1) ? y1f : y0f;
                float w  = ((k & 1) ? wx1 : wx0) * ((k >> 1) ? wy1 : wy0);
                float vd = (xf >= 0.f && xf <= 511.f && yf >= 0.f && yf <= 511.f) ? 1.f : 0.f;
                w *= vd;
                int xi = (int)fminf(fmaxf(xf, 0.f), 511.f);
                int yi = (int)fminf(fmaxf(yf, 0.f), 511.f);
                uint2 iv = *(const uint2*)(base + (size_t)(yi * 512 + xi) * 8);
                vi0 += w * b2f_lo(iv.x);
                vi1 += w * b2f_hi(iv.x);
                vi2 += w * b2f_lo(iv.y);
            }
            si0 += vi0; qi0 += vi0 * vi0;
            si1 += vi1; qi1 += vi1 * vi1;
            si2 += vi2; qi2 += vi2 * vi2;
        }

        // ---- feature sample: 32B per corner per lane (contiguous x4 lanes) ----
        {
            float ix = (gx + 1.f) * 0.5f * 127.f;
            float iy = (gy + 1.f) * 0.5f * 127.f;
            float x0f = floorf(ix), y0f = floorf(iy);
            float x1f = x0f + 1.f, y1f = y0f + 1.f;
            float wx1 = ix - x0f, wx0 = 1.f - wx1;
            float wy1 = iy - y0f, wy0 = 1.f - wy1;
            const unsigned short* fb =
                featsP + ((size_t)v * FT_HW) * 64 + b * 32 + half * 16;
            float val[16];
            #pragma unroll
            for (int c = 0; c < 16; c++) val[c] = 0.f;
            #pragma unroll
            for (int k = 0; k < 4; k++) {
                float xf = (k & 1) ? x1f : x0f;
                float yf = (k >> 1) ? y1f : y0f;
                float w  = ((k & 1) ? wx1 : wx0) * ((k >> 1) ? wy1 : wy0);
                float vd = (xf >= 0.f && xf <= 127.f && yf >= 0.f && yf <= 127.f) ? 1.f : 0.f;
                w *= vd;
                int xi = (int)fminf(fmaxf(xf, 0.f), 127.f);
                int yi = (int)fminf(fmaxf(yf, 0.f), 127.f);
                const uint4* p = (const uint4*)(fb + (size_t)(yi * 128 + xi) * 64);
                #pragma unroll
                for (int q = 0; q < 2; q++) {
                    uint4 f4 = p[q];
                    val[q * 8 + 0] += w * b2f_lo(f4.x);
                    val[q * 8 + 1] += w * b2f_hi(f4.x);
                    val[q * 8 + 2] += w * b2f_lo(f4.y);
                    val[q * 8 + 3] += w * b2f_hi(f4.y);
                    val[q * 8 + 4] += w * b2f_lo(f4.z);
                    val[q * 8 + 5] += w * b2f_hi(f4.z);
                    val[q * 8 + 6] += w * b2f_lo(f4.w);
                    val[q * 8 + 7] += w * b2f_hi(f4.w);
                }
            }
            #pragma unroll
            for (int c = 0; c < 16; c++) {
                sumf[c] += val[c];
                ssqf[c] += val[c] * val[c];
            }
        }
    }

    // finalize: mean / exp(-var)  (in place)
    #pragma unroll
    for (int c = 0; c < 16; c++) {
        float m = sumf[c] * 0.2f;
        float q = ssqf[c] * 0.2f - m * m;
        sumf[c] = m;
        ssqf[c] = expf(-q);
    }
    float mi0 = si0 * 0.2f, mi1 = si1 * 0.2f, mi2 = si2 * 0.2f;
    float ei0 = expf(-(qi0 * 0.2f - mi0 * mi0));
    float ei1 = expf(-(qi1 * 0.2f - mi1 * mi1));
    float ei2 = expf(-(qi2 * 0.2f - mi2 * mi2));

    unsigned int u[24];
    if (half == 0) {
        u[0] = pk(p0, p1);
        u[1] = pk(p2, mi0);
        u[2] = pk(mi1, mi2);
        #pragma unroll
        for (int j = 0; j < 8; j++) u[3 + j] = pk(sumf[2 * j], sumf[2 * j + 1]);
        u[11] = pk(ei0, ei1);
        u[12] = pk(ei2, 0.f);
        #pragma unroll
        for (int j = 0; j < 8; j++) u[13 + j] = pk(ssqf[2 * j], ssqf[2 * j + 1]);
        u[21] = 0u; u[22] = 0u; u[23] = 0u;
    } else {
        #pragma unroll
        for (int j = 0; j < 8; j++) u[j]     = pk(sumf[2 * j], sumf[2 * j + 1]);
        #pragma unroll
        for (int j = 0; j < 8; j++) u[8 + j] = pk(ssqf[2 * j], ssqf[2 * j + 1]);
        #pragma unroll
        for (int j = 16; j < 24; j++) u[j] = 0u;
    }

    // row = 2n + b = gid>>1 ; each lane stores its contiguous 96B half
    uint4* arow = (uint4*)(A + (size_t)(gid >> 1) * KA + half * 48);
    #pragma unroll
    for (int i = 0; i < 6; i++)
        arow[i] = make_uint4(u[4 * i], u[4 * i + 1], u[4 * i + 2], u[4 * i + 3]);
}

// ---------------------------------------------------------------------------
// Kernel 3a: build the B-fragment image of W1 (bf16, mapk-permuted K) ONCE.
// 12288 entries; Bl[o][n][ju] packed-pair layout matching the GEMM's LDS.
// Also stages b1 | W2 | b2 as fp32 into bw[513].
// ---------------------------------------------------------------------------
__global__ __launch_bounds__(256) void stage_w1(
    const float* __restrict__ W1, const float* __restrict__ b1,
    const float* __restrict__ W2, const float* __restrict__ b2,
    unsigned int* __restrict__ Bfrag, float* __restrict__ bw)
{
    int e = blockIdx.x * 256 + threadIdx.x;   // 48 blocks -> 12288
    int ju = e & 3;
    int nn = (e >> 2) & 255;
    int o  = e >> 10;
    int k0 = o * 8 + ju * 2;
    int i0 = mapk(k0), i1 = mapk(k0 + 1);
    float f0 = (i0 >= 0) ? W1[i0 * 256 + nn] : 0.f;
    float f1 = (i1 >= 0) ? W1[i1 * 256 + nn] : 0.f;
    Bfrag[e] = pk(f0, f1);
    if (e < 256)       bw[e] = b1[e];
    else if (e < 512)  bw[e] = W2[e - 256];
    else if (e == 512) bw[e] = b2[0];
}

// ---------------------------------------------------------------------------
// Kernel 3b: MLP as MFMA GEMM, persistent blocks. [256000 x 96]bf16 @
// [96 x 256]bf16 -> relu -> dot(W2) -> softplus -> alpha. B staged into LDS
// with 12 coalesced uint4 loads/thread, then each block loops row tiles.
// mfma_f32_16x16x32_bf16: A[m=lane&15][k=quad*8+j], B[k=quad*8+j][n=lane&15],
// C: col=lane&15, row=quad*4+reg  [verified layouts, learn_hip m89]
// ---------------------------------------------------------------------------
__global__ __launch_bounds__(256) void mlp_gemm(
    const unsigned short* __restrict__ A,     // [256000][96] bf16
    const unsigned int*   __restrict__ Bfrag, // [12288] prebuilt fragments
    const float*          __restrict__ bw,    // b1(256) | W2(256) | b2(1)
    float* __restrict__ out)                  // [256000] = [B][NB]
{
    __shared__ unsigned int Bl[12288];   // 48KB
    __shared__ float b1s[HID];
    __shared__ float W2s[HID];

    const int tid = threadIdx.x;
    {
        const uint4* src = (const uint4*)Bfrag;
        uint4* dst = (uint4*)Bl;
        #pragma unroll
        for (int i = 0; i < 12; i++) dst[i * 256 + tid] = src[i * 256 + tid];
        b1s[tid] = bw[tid];
        W2s[tid] = bw[256 + tid];
    }
    const float b2v = bw[512];
    __syncthreads();

    const int w    = tid >> 6;
    const int lane = tid & 63;
    const int col  = lane & 15;
    const int quad = lane >> 4;
    const unsigned int* bp = Bl + (quad * 256 + col) * 4;

    for (int tile = blockIdx.x; tile < NTILE; tile += GEMM_BLOCKS) {
        const long rowbase = (long)tile * 128 + w * 32;

        f32x4 acc[2][16];
        #pragma unroll
        for (int m = 0; m < 2; m++)
            #pragma unroll
            for (int t = 0; t < 16; t++)
                acc[m][t] = (f32x4){0.f, 0.f, 0.f, 0.f};

        const unsigned short* a0p = A + (rowbase + col) * KA + quad * 8;
        const unsigned short* a1p = a0p + 16 * KA;

        #pragma unroll
        for (int s = 0; s < 3; s++) {
            short8 af0 = *(const short8*)(a0p + s * 32);
            short8 af1 = *(const short8*)(a1p + s * 32);
            #pragma unroll
            for (int t = 0; t < 16; t++) {
                short8 bf = *(const short8*)(bp + s * 4096 + t * 64);
                acc[0][t] = __builtin_amdgcn_mfma_f32_16x16x32_bf16(af0, bf, acc[0][t], 0, 0, 0);
                acc[1][t] = __builtin_amdgcn_mfma_f32_16x16x32_bf16(af1, bf, acc[1][t], 0, 0, 0);
            }
        }

        // epilogue: +b1, relu, dot with W2 (partials over this lane's 16 cols)
        float pm[2][4] = {{0.f, 0.f, 0.f, 0.f}, {0.f, 0.f, 0.f, 0.f}};
        #pragma unroll
        for (int t = 0; t < 16; t++) {
            float b1v = b1s[t * 16 + col];
            float w2v = W2s[t * 16 + col];
            #pragma unroll
            for (int m = 0; m < 2; m++)
                #pragma unroll
                for (int r = 0; r < 4; r++) {
                    float h = fmaxf(acc[m][t][r] + b1v, 0.f);
                    pm[m][r] += h * w2v;
                }
        }
        #pragma unroll
        for (int m = 0; m < 2; m++)
            #pragma unroll
            for (int r = 0; r < 4; r++) {
                float p = pm[m][r];
                p += __shfl_xor(p, 1);
                p += __shfl_xor(p, 2);
                p += __shfl_xor(p, 4);
                p += __shfl_xor(p, 8);
                pm[m][r] = p;
            }

        if (col == 0) {
            #pragma unroll
            for (int m = 0; m < 2; m++)
                #pragma unroll
                for (int r = 0; r < 4; r++) {
                    float x  = pm[m][r] + b2v;
                    float sp = fmaxf(x, 0.f) + log1pf(expf(-fabsf(x)));
                    float alpha = -expm1f(-sp);                 // 1 - exp(-sp)
                    long row = rowbase + m * 16 + quad * 4 + r; // = 2n + b
                    out[(row & 1) * (long)NB + (row >> 1)] = alpha;
                }
        }
    }
}

extern "C" void kernel_launch(void* const* d_in, const int* in_sizes, int n_in,
                              void* d_out, int out_size, void* d_ws, size_t ws_size,
                              hipStream_t stream) {
    const float* imgs   = (const float*)d_in[0];
    const float* feats  = (const float*)d_in[1];
    const float* grid   = (const float*)d_in[2];
    const float* points = (const float*)d_in[3];
    const float* W1     = (const float*)d_in[4];
    const float* b1     = (const float*)d_in[5];
    const float* W2     = (const float*)d_in[6];
    const float* b2     = (const float*)d_in[7];
    float* out = (float*)d_out;

    // workspace: imgsP 20.97MB | featsP 10.49MB | A 49.15MB | Bfrag 48KB | bw 2.05KB
    unsigned short* imgsP  = (unsigned short*)d_ws;
    unsigned short* featsP = imgsP + (size_t)NVIEW * IMG_HW * 8;
    unsigned short* Abuf   = featsP + (size_t)NVIEW * FT_HW * 64;
    unsigned int*   Bfrag  = (unsigned int*)(Abuf + (size_t)2 * NB * KA);
    float*          bwbuf  = (float*)(Bfrag + 12288);

    repack_imgs<<<dim3(5120), dim3(256), 0, stream>>>(imgs, (uint4*)imgsP);
    repack_feats<<<dim3(1280), dim3(256), 0, stream>>>(feats, (uint4*)featsP);
    stage_w1<<<dim3(48), dim3(256), 0, stream>>>(W1, b1, W2, b2, Bfrag, bwbuf);
    gather_features<<<dim3(2000), dim3(256), 0, stream>>>(
        imgsP, featsP, grid, points, Abuf);
    mlp_gemm<<<dim3(GEMM_BLOCKS), dim3(256), 0, stream>>>(
        Abuf, Bfrag, bwbuf, out);
}

// Round 7
// 194.526 us; speedup vs baseline: 3.3912x; 1.1977x over previous
//
#include <hip/hip_runtime.h>

// Problem constants (from reference; all fp32 I/O)
#define NVIEW 5
#define NB    128000          // NBINS = 80*80*20
#define CF    32
#define HID   256
#define KA    96              // padded K for the MLP GEMM
#define IMG_HW 262144         // 512*512
#define FT_HW  16384          // 128*128

typedef __attribute__((ext_vector_type(8))) short short8;   // 8 bf16 (4 VGPRs)
typedef __attribute__((ext_vector_type(4))) float f32x4;    // MFMA accumulator

__device__ __forceinline__ unsigned int f2bf(float f) {
    unsigned int u = __float_as_uint(f);
    return (u + 0x7fffu + ((u >> 16) & 1u)) >> 16;   // RTNE, low 16 bits
}
__device__ __forceinline__ unsigned int pk(float a, float b) {
    return f2bf(a) | (f2bf(b) << 16);
}
__device__ __forceinline__ float b2f_lo(unsigned int u) { return __uint_as_float(u << 16); }
__device__ __forceinline__ float b2f_hi(unsigned int u) { return __uint_as_float(u & 0xffff0000u); }

// A-row layout (96 shorts per row = 2n+b), built by lane halves:
//  half0 (shorts 0..47):  pts(3) mi(3) mf ch0..15 | vi(3) pad vf ch0..15 pad(6)
//  half1 (shorts 48..95): mf ch16..31 (16) vf ch16..31 (16) pad(16)
// mapk: A-row k -> original W1 row i (73-dim input), -1 = zero pad.
__device__ __forceinline__ int mapk(int k) {
    if (k < 22) return k;          // pts + mean img + mean feat0..15
    if (k < 25) return k + 16;     // var img
    if (k == 25) return -1;
    if (k < 42) return k + 15;     // var feat0..15
    if (k < 48) return -1;
    if (k < 64) return k - 26;     // mean feat16..31
    if (k < 80) return k - 7;      // var feat16..31
    return -1;
}

// ---------------------------------------------------------------------------
// Kernel 1: ALL preprocessing in one launch (blockIdx-range split).
//  [0,5120):    repack imgs  -> [V][512][512][8] bf16 (b0c012,pad,b1c012,pad)
//  [5120,6400): repack feats -> [V][128][128][2][32] bf16 (LDS tile)
//  [6400,6448): build W1 B-fragment image + b1|W2|b2 staging
// ---------------------------------------------------------------------------
__global__ __launch_bounds__(256) void prep(
    const float* __restrict__ imgs, const float* __restrict__ feats,
    const float* __restrict__ W1, const float* __restrict__ b1,
    const float* __restrict__ W2, const float* __restrict__ b2,
    uint4* __restrict__ imgsP, uint4* __restrict__ featsP,
    unsigned int* __restrict__ Bfrag, float* __restrict__ bw)
{
    const int bidx = blockIdx.x;
    const int t = threadIdx.x;
    if (bidx < 5120) {
        // ---- images ----
        int gid = bidx * 256 + t;               // 1,310,720
        int v  = gid >> 18;
        int px = gid & (IMG_HW - 1);
        const float* base = imgs + (size_t)v * 6 * IMG_HW + px;
        uint4 o;
        o.x = f2bf(base[0 * IMG_HW]) | (f2bf(base[1 * IMG_HW]) << 16);
        o.y = f2bf(base[2 * IMG_HW]);
        o.z = f2bf(base[3 * IMG_HW]) | (f2bf(base[4 * IMG_HW]) << 16);
        o.w = f2bf(base[5 * IMG_HW]);
        imgsP[gid] = o;
    } else if (bidx < 6400) {
        // ---- features via LDS tile ----
        __shared__ unsigned short tile[64][65];
        const int pixbase = (bidx - 5120) * 64;
        const int v   = pixbase >> 14;
        const int rem = pixbase & 16383;
        {
            const int p = t & 63;
            const int s = t >> 6;
            #pragma unroll
            for (int it = 0; it < 16; it++) {
                int plane = it * 4 + s;         // = b*32 + ch
                tile[plane][p] =
                    (unsigned short)f2bf(feats[((size_t)v * 64 + plane) * FT_HW + rem + p]);
            }
        }
        __syncthreads();
        {
            const int q = t & 7;
            #pragma unroll
            for (int it = 0; it < 2; it++) {
                int p = it * 32 + (t >> 3);
                uint4 o;
                o.x = (unsigned)tile[q * 8 + 0][p] | ((unsigned)tile[q * 8 + 1][p] << 16);
                o.y = (unsigned)tile[q * 8 + 2][p] | ((unsigned)tile[q * 8 + 3][p] << 16);
                o.z = (unsigned)tile[q * 8 + 4][p] | ((unsigned)tile[q * 8 + 5][p] << 16);
                o.w = (unsigned)tile[q * 8 + 6][p] | ((unsigned)tile[q * 8 + 7][p] << 16);
                featsP[(size_t)(pixbase + p) * 8 + q] = o;
            }
        }
    } else {
        // ---- W1 fragment image (mapk-permuted, bf16 pairs) ----
        int e = (bidx - 6400) * 256 + t;        // [0, 12288)
        int ju = e & 3;
        int nn = (e >> 2) & 255;
        int o  = e >> 10;
        int k0 = o * 8 + ju * 2;
        int i0 = mapk(k0), i1 = mapk(k0 + 1);
        float f0 = (i0 >= 0) ? W1[i0 * 256 + nn] : 0.f;
        float f1 = (i1 >= 0) ? W1[i1 * 256 + nn] : 0.f;
        Bfrag[e] = pk(f0, f1);
        if (e < 256)       bw[e] = b1[e];
        else if (e < 512)  bw[e] = W2[e - 256];
        else if (e == 512) bw[e] = b2[0];
    }
}

// ---------------------------------------------------------------------------
// Kernel 2: FUSED gather + MLP. One block = 64 points x 4 lanes = 128 GEMM
// rows = one tile. Gather halves -> LDS (stride-13-uint4 rows), one barrier,
// then mfma_f32_16x16x32_bf16 against LDS-staged B fragments, fused epilogue
// (relu -> dot W2 -> softplus -> alpha) with direct scattered out stores.
// No A-matrix round-trip through HBM.
// mfma: A[m=lane&15][k=quad*8+j], B[k][n=lane&15], C: col=lane&15,
// row=quad*4+reg  [verified layouts, learn_hip m89]
// ---------------------------------------------------------------------------
#define AROW 13   // uint4s per LDS A-row (12 data + 1 pad for bank spread)

__global__ __launch_bounds__(256, 2) void fused_gather_mlp(
    const unsigned short* __restrict__ imgsP,   // [V][512][512][8] bf16
    const unsigned short* __restrict__ featsP,  // [V][128][128][2][32] bf16
    const float* __restrict__ grid,             // [V][NB][2]
    const float* __restrict__ points,           // [NB][3]
    const unsigned int*   __restrict__ Bfrag,   // [12288] prebuilt fragments
    const float*          __restrict__ bw,      // b1(256) | W2(256) | b2(1)
    float* __restrict__ out)                    // [256000] = [B][NB]
{
    __shared__ unsigned int Bl[12288];          // 48 KB
    __shared__ uint4 As4[128 * AROW];           // 26.6 KB
    __shared__ float b1s[HID];
    __shared__ float W2s[HID];

    const int tid = threadIdx.x;

    // stage B fragments + biases (coalesced; Bfrag is L2-hot, 48 KB)
    {
        const uint4* src = (const uint4*)Bfrag;
        uint4* dst = (uint4*)Bl;
        #pragma unroll
        for (int i = 0; i < 12; i++) dst[i * 256 + tid] = src[i * 256 + tid];
        b1s[tid] = bw[tid];
        W2s[tid] = bw[256 + tid];
    }
    const float b2v = bw[512];

    // ================= gather phase =================
    const int n    = blockIdx.x * 64 + (tid >> 2);
    const int b    = (tid >> 1) & 1;
    const int half = tid & 1;

    float sumf[16], ssqf[16];
    #pragma unroll
    for (int c = 0; c < 16; c++) { sumf[c] = 0.f; ssqf[c] = 0.f; }
    float si0 = 0.f, si1 = 0.f, si2 = 0.f;
    float qi0 = 0.f, qi1 = 0.f, qi2 = 0.f;
    float p0 = 0.f, p1 = 0.f, p2 = 0.f;
    if (half == 0) {
        p0 = points[n * 3 + 0];
        p1 = points[n * 3 + 1];
        p2 = points[n * 3 + 2];
    }

    #pragma unroll
    for (int v = 0; v < NVIEW; v++) {
        const float2 g = ((const float2*)grid)[v * NB + n];
        const float gx = g.x, gy = g.y;

        // ---- image sample (half0 lanes only): 8B per corner ----
        if (half == 0) {
            float ix = (gx + 1.f) * 0.5f * 511.f;
            float iy = (gy + 1.f) * 0.5f * 511.f;
            float x0f = floorf(ix), y0f = floorf(iy);
            float x1f = x0f + 1.f, y1f = y0f + 1.f;
            float wx1 = ix - x0f, wx0 = 1.f - wx1;
            float wy1 = iy - y0f, wy0 = 1.f - wy1;
            float vi0 = 0.f, vi1 = 0.f, vi2 = 0.f;
            const unsigned short* base = imgsP + ((size_t)v * IMG_HW) * 8 + b * 4;
            #pragma unroll
            for (int k = 0; k < 4; k++) {
                float xf = (k & 1) ? x1f : x0f;
                float yf = (k >> 1) ? y1f : y0f;
                float w  = ((k & 1) ? wx1 : wx0) * ((k >> 1) ? wy1 : wy0);
                float vd = (xf >= 0.f && xf <= 511.f && yf >= 0.f && yf <= 511.f) ? 1.f : 0.f;
                w *= vd;
                int xi = (int)fminf(fmaxf(xf, 0.f), 511.f);
                int yi = (int)fminf(fmaxf(yf, 0.f), 511.f);
                uint2 iv = *(const uint2*)(base + (size_t)(yi * 512 + xi) * 8);
                vi0 += w * b2f_lo(iv.x);
                vi1 += w * b2f_hi(iv.x);
                vi2 += w * b2f_lo(iv.y);
            }
            si0 += vi0; qi0 += vi0 * vi0;
            si1 += vi1; qi1 += vi1 * vi1;
            si2 += vi2; qi2 += vi2 * vi2;
        }

        // ---- feature sample: 32B per corner per lane (contiguous x4 lanes) ----
        {
            float ix = (gx + 1.f) * 0.5f * 127.f;
            float iy = (gy + 1.f) * 0.5f * 127.f;
            float x0f = floorf(ix), y0f = floorf(iy);
            float x1f = x0f + 1.f, y1f = y0f + 1.f;
            float wx1 = ix - x0f, wx0 = 1.f - wx1;
            float wy1 = iy - y0f, wy0 = 1.f - wy1;
            const unsigned short* fb =
                featsP + ((size_t)v * FT_HW) * 64 + b * 32 + half * 16;
            float val[16];
            #pragma unroll
            for (int c = 0; c < 16; c++) val[c] = 0.f;
            #pragma unroll
            for (int k = 0; k < 4; k++) {
                float xf = (k & 1) ? x1f : x0f;
                float yf = (k >> 1) ? y1f : y0f;
                float w  = ((k & 1) ? wx1 : wx0) * ((k >> 1) ? wy1 : wy0);
                float vd = (xf >= 0.f && xf <= 127.f && yf >= 0.f && yf <= 127.f) ? 1.f : 0.f;
                w *= vd;
                int xi = (int)fminf(fmaxf(xf, 0.f), 127.f);
                int yi = (int)fminf(fmaxf(yf, 0.f), 127.f);
                const uint4* p = (const uint4*)(fb + (size_t)(yi * 128 + xi) * 64);
                #pragma unroll
                for (int q = 0; q < 2; q++) {
                    uint4 f4 = p[q];
                    val[q * 8 + 0] += w * b2f_lo(f4.x);
                    val[q * 8 + 1] += w * b2f_hi(f4.x);
                    val[q * 8 + 2] += w * b2f_lo(f4.y);
                    val[q * 8 + 3] += w * b2f_hi(f4.y);
                    val[q * 8 + 4] += w * b2f_lo(f4.z);
                    val[q * 8 + 5] += w * b2f_hi(f4.z);
                    val[q * 8 + 6] += w * b2f_lo(f4.w);
                    val[q * 8 + 7] += w * b2f_hi(f4.w);
                }
            }
            #pragma unroll
            for (int c = 0; c < 16; c++) {
                sumf[c] += val[c];
                ssqf[c] += val[c] * val[c];
            }
        }
    }

    // finalize mean / exp(-var)
    #pragma unroll
    for (int c = 0; c < 16; c++) {
        float m = sumf[c] * 0.2f;
        float q = ssqf[c] * 0.2f - m * m;
        sumf[c] = m;
        ssqf[c] = expf(-q);
    }
    float mi0 = si0 * 0.2f, mi1 = si1 * 0.2f, mi2 = si2 * 0.2f;
    float ei0 = expf(-(qi0 * 0.2f - mi0 * mi0));
    float ei1 = expf(-(qi1 * 0.2f - mi1 * mi1));
    float ei2 = expf(-(qi2 * 0.2f - mi2 * mi2));

    unsigned int u[24];
    if (half == 0) {
        u[0] = pk(p0, p1);
        u[1] = pk(p2, mi0);
        u[2] = pk(mi1, mi2);
        #pragma unroll
        for (int j = 0; j < 8; j++) u[3 + j] = pk(sumf[2 * j], sumf[2 * j + 1]);
        u[11] = pk(ei0, ei1);
        u[12] = pk(ei2, 0.f);
        #pragma unroll
        for (int j = 0; j < 8; j++) u[13 + j] = pk(ssqf[2 * j], ssqf[2 * j + 1]);
        u[21] = 0u; u[22] = 0u; u[23] = 0u;
    } else {
        #pragma unroll
        for (int j = 0; j < 8; j++) u[j]     = pk(sumf[2 * j], sumf[2 * j + 1]);
        #pragma unroll
        for (int j = 0; j < 8; j++) u[8 + j] = pk(ssqf[2 * j], ssqf[2 * j + 1]);
        #pragma unroll
        for (int j = 16; j < 24; j++) u[j] = 0u;
    }

    // write my 96B half-row to LDS: local row = tid>>1 in [0,128)
    {
        uint4* arow = &As4[(tid >> 1) * AROW + half * 6];
        #pragma unroll
        for (int i = 0; i < 6; i++)
            arow[i] = make_uint4(u[4 * i], u[4 * i + 1], u[4 * i + 2], u[4 * i + 3]);
    }
    __syncthreads();   // As4 + Bl + b1s/W2s all ready

    // ================= GEMM phase =================
    const int w    = tid >> 6;
    const int lane = tid & 63;
    const int col  = lane & 15;
    const int quad = lane >> 4;
    const long rowbase = (long)blockIdx.x * 128 + w * 32;

    f32x4 acc[2][16];
    #pragma unroll
    for (int m = 0; m < 2; m++)
        #pragma unroll
        for (int t = 0; t < 16; t++)
            acc[m][t] = (f32x4){0.f, 0.f, 0.f, 0.f};

    const unsigned int* bp = Bl + (quad * 256 + col) * 4;

    #pragma unroll
    for (int s = 0; s < 3; s++) {
        short8 af0 = *(const short8*)&As4[(w * 32 + col)      * AROW + s * 4 + quad];
        short8 af1 = *(const short8*)&As4[(w * 32 + 16 + col) * AROW + s * 4 + quad];
        #pragma unroll
        for (int t = 0; t < 16; t++) {
            short8 bf = *(const short8*)(bp + s * 4096 + t * 64);
            acc[0][t] = __builtin_amdgcn_mfma_f32_16x16x32_bf16(af0, bf, acc[0][t], 0, 0, 0);
            acc[1][t] = __builtin_amdgcn_mfma_f32_16x16x32_bf16(af1, bf, acc[1][t], 0, 0, 0);
        }
    }

    // epilogue: +b1, relu, dot W2, cross-col reduce, softplus -> alpha
    float pm[2][4] = {{0.f, 0.f, 0.f, 0.f}, {0.f, 0.f, 0.f, 0.f}};
    #pragma unroll
    for (int t = 0; t < 16; t++) {
        float b1v = b1s[t * 16 + col];
        float w2v = W2s[t * 16 + col];
        #pragma unroll
        for (int m = 0; m < 2; m++)
            #pragma unroll
            for (int r = 0; r < 4; r++) {
                float h = fmaxf(acc[m][t][r] + b1v, 0.f);
                pm[m][r] += h * w2v;
            }
    }
    #pragma unroll
    for (int m = 0; m < 2; m++)
        #pragma unroll
        for (int r = 0; r < 4; r++) {
            float p = pm[m][r];
            p += __shfl_xor(p, 1);
            p += __shfl_xor(p, 2);
            p += __shfl_xor(p, 4);
            p += __shfl_xor(p, 8);
            pm[m][r] = p;
        }

    if (col == 0) {
        #pragma unroll
        for (int m = 0; m < 2; m++)
            #pragma unroll
            for (int r = 0; r < 4; r++) {
                float x  = pm[m][r] + b2v;
                float sp = fmaxf(x, 0.f) + log1pf(expf(-fabsf(x)));  // softplus
                float alpha = -expm1f(-sp);                          // 1 - exp(-sp)
                long row = rowbase + m * 16 + quad * 4 + r;          // = 2n + b
                out[(row & 1) * (long)NB + (row >> 1)] = alpha;
            }
    }
}

extern "C" void kernel_launch(void* const* d_in, const int* in_sizes, int n_in,
                              void* d_out, int out_size, void* d_ws, size_t ws_size,
                              hipStream_t stream) {
    const float* imgs   = (const float*)d_in[0];
    const float* feats  = (const float*)d_in[1];
    const float* grid   = (const float*)d_in[2];
    const float* points = (const float*)d_in[3];
    const float* W1     = (const float*)d_in[4];
    const float* b1     = (const float*)d_in[5];
    const float* W2     = (const float*)d_in[6];
    const float* b2     = (const float*)d_in[7];
    float* out = (float*)d_out;

    // workspace: imgsP 20.97MB | featsP 10.49MB | Bfrag 48KB | bw 2.05KB
    unsigned short* imgsP  = (unsigned short*)d_ws;
    unsigned short* featsP = imgsP + (size_t)NVIEW * IMG_HW * 8;
    unsigned int*   Bfrag  = (unsigned int*)(featsP + (size_t)NVIEW * FT_HW * 64);
    float*          bwbuf  = (float*)(Bfrag + 12288);

    prep<<<dim3(6448), dim3(256), 0, stream>>>(
        imgs, feats, W1, b1, W2, b2,
        (uint4*)imgsP, (uint4*)featsP, Bfrag, bwbuf);
    fused_gather_mlp<<<dim3(2000), dim3(256), 0, stream>>>(
        imgsP, featsP, grid, points, Bfrag, bwbuf, out);
}